// Round 1
// baseline (789.819 us; speedup 1.0000x reference)
//
#include <hip/hip_runtime.h>
#include <hip/hip_bf16.h>

#define N_NODES 50000
#define N_EDGES 800000
#define DF 128

// LDS row strides (in ushorts), padded +8 bf16 to break ds_read_b128 bank conflicts
#define ES 264   // edge tile: rows of 256 bf16 + 8 pad  (stride 528 B = 33*16 B)
#define HS 136   // hidden tile: rows of 128 bf16 + 8 pad (stride 272 B = 17*16 B)

typedef __bf16 bf16x8 __attribute__((ext_vector_type(8)));
typedef float f32x4 __attribute__((ext_vector_type(4)));
typedef unsigned int uint4v __attribute__((ext_vector_type(4)));
typedef unsigned short us4 __attribute__((ext_vector_type(4)));

__device__ __forceinline__ unsigned short f2bf(float f) {
  unsigned u = __builtin_bit_cast(unsigned, f);
  u += 0x7FFFu + ((u >> 16) & 1u);   // round-to-nearest-even
  return (unsigned short)(u >> 16);
}

// Pack fp32 row-major W[K][128] into bf16 MFMA B-fragment order:
// out[((ct*kpc + kc)*64 + lane)*8 + j] = bf16(W[kc*32 + (lane>>4)*8 + j][ct*16 + (lane&15)])
__global__ void pack_weights(const float* __restrict__ W,
                             unsigned short* __restrict__ out, int K) {
  const int idx = blockIdx.x * blockDim.x + threadIdx.x;
  const int kpc = K >> 5;
  const int total = 8 * kpc * 64;
  if (idx >= total) return;
  const int l = idx & 63;
  const int blk = idx >> 6;
  const int ct = blk / kpc;
  const int kc = blk % kpc;
  const int col = ct * 16 + (l & 15);
  const int k0 = kc * 32 + (l >> 4) * 8;
  unsigned short tmp[8];
#pragma unroll
  for (int j = 0; j < 8; ++j)
    tmp[j] = f2bf(W[(size_t)(k0 + j) * DF + col]);
  us4 lo = { tmp[0], tmp[1], tmp[2], tmp[3] };
  us4 hi = { tmp[4], tmp[5], tmp[6], tmp[7] };
  us4* o = (us4*)(out + (size_t)idx * 8);
  o[0] = lo;
  o[1] = hi;
}

// One EdgeConv layer. Block = 256 threads (4 waves) handles 64 edges.
// Wave w computes output cols [w*32, w*32+32) for all 64 edges.
template<bool WRITE_MSG>
__global__ __launch_bounds__(256)
void layer_kernel(const float* __restrict__ feat_in,
                  const int* __restrict__ src_idx,
                  const int* __restrict__ dst_idx,
                  const unsigned short* __restrict__ w1p,
                  const float* __restrict__ b1,
                  const unsigned short* __restrict__ w2p,
                  const float* __restrict__ b2,
                  float* __restrict__ feat_out,
                  float* __restrict__ msg_out) {
  __shared__ unsigned short edge_s[64 * ES];
  __shared__ unsigned short h_s[64 * HS];
  __shared__ int dst_s[64];

  const int t = threadIdx.x;
  const int e0 = blockIdx.x * 64;

  // ---- stage: gather x_i=x[dst], x_j=x[src]; edge = [x_i, x_j - x_i] as bf16 ----
  {
    const int e = t >> 2, q = t & 3;
    const int ge = e0 + e;
    const int si = src_idx[ge];
    const int di = dst_idx[ge];
    if (q == 0) dst_s[e] = di;
    const float4* xi = (const float4*)(feat_in + (size_t)di * DF) + q * 8;
    const float4* xj = (const float4*)(feat_in + (size_t)si * DF) + q * 8;
    unsigned short* ei = &edge_s[e * ES + q * 32];
    unsigned short* ed = ei + 128;
#pragma unroll
    for (int i = 0; i < 8; ++i) {
      float4 vi = xi[i];
      float4 vj = xj[i];
      us4 pi = { f2bf(vi.x), f2bf(vi.y), f2bf(vi.z), f2bf(vi.w) };
      us4 pd = { f2bf(vj.x - vi.x), f2bf(vj.y - vi.y),
                 f2bf(vj.z - vi.z), f2bf(vj.w - vi.w) };
      *(us4*)(ei + i * 4) = pi;
      *(us4*)(ed + i * 4) = pd;
    }
  }
  __syncthreads();

  const int w = t >> 6;
  const int l = t & 63;
  const int l15 = l & 15;
  const int lg = l >> 4;

  // ---- GEMM1: edge[64x256] @ W1[256x128] ----
  f32x4 acc[4][2] = {};
  const uint4v* w1v = (const uint4v*)w1p;
#pragma unroll
  for (int kc = 0; kc < 8; ++kc) {
    bf16x8 afr[4];
#pragma unroll
    for (int rt = 0; rt < 4; ++rt)
      afr[rt] = __builtin_bit_cast(bf16x8,
          *(const uint4v*)&edge_s[(rt * 16 + l15) * ES + kc * 32 + lg * 8]);
#pragma unroll
    for (int c = 0; c < 2; ++c) {
      bf16x8 bfr = __builtin_bit_cast(bf16x8, w1v[((w * 2 + c) * 8 + kc) * 64 + l]);
#pragma unroll
      for (int rt = 0; rt < 4; ++rt)
        acc[rt][c] = __builtin_amdgcn_mfma_f32_16x16x32_bf16(afr[rt], bfr, acc[rt][c], 0, 0, 0);
    }
  }

  // ---- bias + ReLU -> h_s (bf16) ----
#pragma unroll
  for (int c = 0; c < 2; ++c) {
    const int col = w * 32 + c * 16 + l15;
    const float bv = b1[col];
#pragma unroll
    for (int rt = 0; rt < 4; ++rt) {
#pragma unroll
      for (int r = 0; r < 4; ++r) {
        float v = acc[rt][c][r] + bv;
        v = v > 0.f ? v : 0.f;
        h_s[(rt * 16 + lg * 4 + r) * HS + col] = f2bf(v);
      }
    }
  }
  __syncthreads();

  // ---- GEMM2: h[64x128] @ W2[128x128] ----
  f32x4 acc2[4][2] = {};
  const uint4v* w2v = (const uint4v*)w2p;
#pragma unroll
  for (int kc = 0; kc < 4; ++kc) {
    bf16x8 afr[4];
#pragma unroll
    for (int rt = 0; rt < 4; ++rt)
      afr[rt] = __builtin_bit_cast(bf16x8,
          *(const uint4v*)&h_s[(rt * 16 + l15) * HS + kc * 32 + lg * 8]);
#pragma unroll
    for (int c = 0; c < 2; ++c) {
      bf16x8 bfr = __builtin_bit_cast(bf16x8, w2v[((w * 2 + c) * 4 + kc) * 64 + l]);
#pragma unroll
      for (int rt = 0; rt < 4; ++rt)
        acc2[rt][c] = __builtin_amdgcn_mfma_f32_16x16x32_bf16(afr[rt], bfr, acc2[rt][c], 0, 0, 0);
    }
  }

  // ---- epilogue: bias, msg write, atomic scatter-add at dst ----
#pragma unroll
  for (int c = 0; c < 2; ++c) {
    const int col = w * 32 + c * 16 + l15;
    const float bv = b2[col];
#pragma unroll
    for (int rt = 0; rt < 4; ++rt) {
#pragma unroll
      for (int r = 0; r < 4; ++r) {
        const int row = rt * 16 + lg * 4 + r;
        const float v = acc2[rt][c][r] + bv;
        if (WRITE_MSG)
          msg_out[(size_t)(e0 + row) * DF + col] = v;
        unsafeAtomicAdd(&feat_out[(size_t)dst_s[row] * DF + col], v);
      }
    }
  }
}

extern "C" void kernel_launch(void* const* d_in, const int* in_sizes, int n_in,
                              void* d_out, int out_size, void* d_ws, size_t ws_size,
                              hipStream_t stream) {
  const float* x    = (const float*)d_in[0];
  const int*   eidx = (const int*)d_in[1];
  const float* W1_0 = (const float*)d_in[2];
  const float* b1_0 = (const float*)d_in[3];
  const float* W2_0 = (const float*)d_in[4];
  const float* b2_0 = (const float*)d_in[5];
  const float* W1_1 = (const float*)d_in[6];
  const float* b1_1 = (const float*)d_in[7];
  const float* W2_1 = (const float*)d_in[8];
  const float* b2_1 = (const float*)d_in[9];

  const int* src = eidx;            // edge_index[0]
  const int* dst = eidx + N_EDGES;  // edge_index[1]

  float* feat2 = (float*)d_out;
  float* msg2  = feat2 + (size_t)N_NODES * DF;

  // workspace: feat1 (25.6 MB) + packed bf16 weights (192 KB)
  float* feat1 = (float*)d_ws;
  unsigned short* w1p0 = (unsigned short*)((char*)d_ws + (size_t)N_NODES * DF * sizeof(float));
  unsigned short* w2p0 = w1p0 + 256 * 128;
  unsigned short* w1p1 = w2p0 + 128 * 128;
  unsigned short* w2p1 = w1p1 + 256 * 128;

  hipMemsetAsync(feat1, 0, (size_t)N_NODES * DF * sizeof(float), stream);
  hipMemsetAsync(feat2, 0, (size_t)N_NODES * DF * sizeof(float), stream);

  pack_weights<<<16, 256, 0, stream>>>(W1_0, w1p0, 256);
  pack_weights<<<8, 256, 0, stream>>>(W2_0, w2p0, 128);
  pack_weights<<<16, 256, 0, stream>>>(W1_1, w1p1, 256);
  pack_weights<<<8, 256, 0, stream>>>(W2_1, w2p1, 128);

  layer_kernel<false><<<N_EDGES / 64, 256, 0, stream>>>(
      x, src, dst, w1p0, b1_0, w2p0, b2_0, feat1, nullptr);
  layer_kernel<true><<<N_EDGES / 64, 256, 0, stream>>>(
      feat1, src, dst, w1p1, b1_1, w2p1, b2_1, feat2, msg2);
}